// Round 1
// baseline (420.146 us; speedup 1.0000x reference)
//
#include <hip/hip_runtime.h>

#define NN 8192
#define CHUNKS 64
#define ROWS_PER_CHUNK (NN / CHUNKS)   // 128

// ws layout (floats):
//   w[NN]                 : norm[i] * V[i]
//   diag[NN]              : ts[i,i]^2
//   partial[CHUNKS * NN]  : partial weighted column sums

// --- K1: per-row sum of squares -> w[i], diag[i] ---------------------------
__global__ void row_pass(const float* __restrict__ ts,
                         const float* __restrict__ state,
                         float* __restrict__ w,
                         float* __restrict__ diag_out) {
    const int row = blockIdx.x;
    const float4* rowp = reinterpret_cast<const float4*>(ts + (size_t)row * NN);
    float sum = 0.f;
    // 256 threads x 8 float4 = 8192 floats
    for (int k = threadIdx.x; k < NN / 4; k += 256) {
        float4 v = rowp[k];
        sum += v.x * v.x + v.y * v.y + v.z * v.z + v.w * v.w;
    }
    // wave-64 reduce
    #pragma unroll
    for (int off = 32; off > 0; off >>= 1) sum += __shfl_down(sum, off);
    __shared__ float red[4];
    const int lane = threadIdx.x & 63;
    const int wid  = threadIdx.x >> 6;
    if (lane == 0) red[wid] = sum;
    __syncthreads();
    if (threadIdx.x == 0) {
        float total = red[0] + red[1] + red[2] + red[3];
        float d = ts[(size_t)row * NN + row];
        d = d * d;
        float norm = fminf(d / (total - d), 1.0f);
        float V = state[3 * row + 2];
        w[row] = norm * V;
        diag_out[row] = d;
    }
}

// --- K2: partial weighted column sums --------------------------------------
// blockIdx.x in [0, NN/1024): column tile (256 threads x float4 = 1024 cols)
// blockIdx.y in [0, CHUNKS):  row chunk of ROWS_PER_CHUNK rows
__global__ void col_pass(const float* __restrict__ ts,
                         const float* __restrict__ w,
                         float* __restrict__ partial) {
    const int colBase = blockIdx.x * 1024 + threadIdx.x * 4;
    const int row0 = blockIdx.y * ROWS_PER_CHUNK;
    float4 acc = {0.f, 0.f, 0.f, 0.f};
    const float* base = ts + (size_t)row0 * NN + colBase;
    #pragma unroll 4
    for (int r = 0; r < ROWS_PER_CHUNK; ++r) {
        const float wi = w[row0 + r];           // wave-uniform -> scalar load
        float4 v = *reinterpret_cast<const float4*>(base + (size_t)r * NN);
        acc.x += wi * v.x * v.x;
        acc.y += wi * v.y * v.y;
        acc.z += wi * v.z * v.z;
        acc.w += wi * v.w * v.w;
    }
    *reinterpret_cast<float4*>(partial + (size_t)blockIdx.y * NN + colBase) = acc;
}

// --- K3: reduce partials + all O(N) elementwise math -----------------------
__global__ void finalize(const float* __restrict__ state,
                         const float* __restrict__ betas,
                         const float* __restrict__ deltas,
                         const float* __restrict__ cs,
                         const float* __restrict__ ps,
                         const float* __restrict__ w,
                         const float* __restrict__ diag,
                         const float* __restrict__ partial,
                         float* __restrict__ out) {
    const int j = blockIdx.x * blockDim.x + threadIdx.x;
    if (j >= NN) return;
    float coup = 0.f;
    #pragma unroll 8
    for (int c = 0; c < CHUNKS; ++c) coup += partial[(size_t)c * NN + j];
    const float dj = diag[j];
    coup -= w[j] * dj;                          // remove i==j term

    const float U = state[3 * j + 0];
    const float I = state[3 * j + 1];
    const float V = state[3 * j + 2];
    const float b2 = betas[j] * betas[j];
    const float d2 = deltas[j] * deltas[j];
    const float p2 = ps[j] * ps[j];
    const float c2 = cs[j] * cs[j];
    const float bUV = b2 * U * V;

    out[3 * j + 0] = -bUV;
    out[3 * j + 1] = bUV - d2 * I;
    out[3 * j + 2] = p2 * I - c2 * V - dj + coup;
}

extern "C" void kernel_launch(void* const* d_in, const int* in_sizes, int n_in,
                              void* d_out, int out_size, void* d_ws, size_t ws_size,
                              hipStream_t stream) {
    // inputs: 0:t 1:state 2:betas 3:deltas 4:cs 5:ps 6:ts
    const float* state  = (const float*)d_in[1];
    const float* betas  = (const float*)d_in[2];
    const float* deltas = (const float*)d_in[3];
    const float* cs     = (const float*)d_in[4];
    const float* ps     = (const float*)d_in[5];
    const float* ts     = (const float*)d_in[6];
    float* out = (float*)d_out;

    float* w       = (float*)d_ws;
    float* diag    = w + NN;
    float* partial = diag + NN;

    row_pass<<<NN, 256, 0, stream>>>(ts, state, w, diag);

    dim3 g2(NN / 1024, CHUNKS);
    col_pass<<<g2, 256, 0, stream>>>(ts, w, partial);

    finalize<<<NN / 256, 256, 0, stream>>>(state, betas, deltas, cs, ps,
                                           w, diag, partial, out);
}